// Round 1
// 760.238 us; speedup vs baseline: 1.3333x; 1.3333x over previous
//
#include <hip/hip_runtime.h>
#include <hip/hip_bf16.h>
#include <math.h>

#define NNODES 50000
#define NEDGES 800000
#define HD     256   // HEADS*DHEAD
#define CW     640   // comb width: q(256) | qwe(64) | v(256) | skip(64)

typedef __hip_bfloat16 bf16;
typedef unsigned short u16;
typedef unsigned char  u8;
typedef unsigned int   u32;
typedef __attribute__((ext_vector_type(8))) short bf16x8;
typedef __attribute__((ext_vector_type(4))) float f32x4;
typedef __attribute__((ext_vector_type(2))) float f32x2;

__device__ __forceinline__ float lo16f(u32 u) { return __uint_as_float(u << 16); }
__device__ __forceinline__ float hi16f(u32 u) { return __uint_as_float(u & 0xFFFF0000u); }
__device__ __forceinline__ short f2s(float v) { __hip_bfloat16 h = __float2bfloat16(v); return *(short*)&h; }

// ---------------- CSR build ----------------
__global__ void hist_kernel(const int* __restrict__ dst, int* __restrict__ deg, int E) {
    int e = blockIdx.x * 256 + threadIdx.x;
    if (e < E) atomicAdd(&deg[dst[e]], 1);
}

__global__ void scanA(const int* __restrict__ deg, int* __restrict__ locincl,
                      int* __restrict__ blocksum, int n) {
    int tid = threadIdx.x;
    int i = blockIdx.x * 256 + tid;
    int v = (i < n) ? deg[i] : 0;
    int lane = tid & 63, w = tid >> 6;
    int s = v;
    #pragma unroll
    for (int off = 1; off < 64; off <<= 1) {
        int t = __shfl_up(s, off);
        if (lane >= off) s += t;
    }
    __shared__ int wsum[4];
    if (lane == 63) wsum[w] = s;
    __syncthreads();
    for (int ww = 0; ww < w; ww++) s += wsum[ww];
    if (i < n) locincl[i] = s;
    if (tid == 255) blocksum[blockIdx.x] = s;
}

__global__ void scanB(const int* __restrict__ blocksum, int* __restrict__ blockoff,
                      int nb, int* __restrict__ rowptr, int n) {
    int tid = threadIdx.x;
    int v = (tid < nb) ? blocksum[tid] : 0;
    int lane = tid & 63, w = tid >> 6;
    int s = v;
    #pragma unroll
    for (int off = 1; off < 64; off <<= 1) {
        int t = __shfl_up(s, off);
        if (lane >= off) s += t;
    }
    __shared__ int wsum[4];
    if (lane == 63) wsum[w] = s;
    __syncthreads();
    for (int ww = 0; ww < w; ww++) s += wsum[ww];
    if (tid < nb) blockoff[tid] = s - v;
    if (tid == 255) rowptr[n] = s;
}

__global__ void scanC(const int* __restrict__ deg, const int* __restrict__ locincl,
                      const int* __restrict__ blockoff,
                      int* __restrict__ rowptr, int* __restrict__ cursor, int n) {
    int i = blockIdx.x * 256 + threadIdx.x;
    if (i < n) {
        int ex = locincl[i] - deg[i] + blockoff[blockIdx.x];
        rowptr[i] = ex;
        cursor[i] = ex;
    }
}

__global__ void scatter_kernel(const int* __restrict__ src, const int* __restrict__ dst,
                               int* __restrict__ cursor, int2* __restrict__ csr2, int E) {
    int e = blockIdx.x * 256 + threadIdx.x;
    if (e < E) {
        int d = dst[e];
        int p = atomicAdd(&cursor[d], 1);
        csr2[p] = make_int2(src[e], e);
    }
}

// WqWe[c][h*16+j] = sum_d Wq[c, h*64+d] * We[j, h*64+d]; row c==FIN is the bq-derived bias.
__global__ void wqwe_kernel(const float* __restrict__ Wq, const float* __restrict__ bq,
                            const float* __restrict__ We, float* __restrict__ out, int FIN) {
    int c = blockIdx.x;
    int t = threadIdx.x;
    int h = t >> 4, j = t & 15;
    const float* qrow = (c == FIN) ? bq : (Wq + (size_t)c * HD);
    float s = 0.f;
    #pragma unroll 8
    for (int d = 0; d < 64; d++) s += qrow[h * 64 + d] * We[j * HD + h * 64 + d];
    out[c * 64 + t] = s;
}

// ---- weight packs: n-major bf16 [N][K] + fp32 bias ----
// 640 rows: q(256) | qwe(64) | v(256) | skip(64)
__global__ void pack640(const float* __restrict__ Wq, const float* __restrict__ bq,
                        const float* __restrict__ wqwe,
                        const float* __restrict__ Wv, const float* __restrict__ bv,
                        const float* __restrict__ Ws, const float* __restrict__ bs,
                        bf16* __restrict__ Wc, float* __restrict__ b, int K) {
    int n = blockIdx.x, c = threadIdx.x;
    float v, bb;
    if (n < 256)      { v = Wq[(size_t)c * 256 + n];       bb = bq[n]; }
    else if (n < 320) { v = wqwe[c * 64 + (n - 256)];      bb = wqwe[K * 64 + (n - 256)]; }
    else if (n < 576) { v = Wv[(size_t)c * 256 + (n - 320)]; bb = bv[n - 320]; }
    else              { v = Ws[(size_t)c * 64 + (n - 576)];  bb = bs[n - 576]; }
    Wc[(size_t)n * K + c] = __float2bfloat16(v);
    if (c == 0) b[n] = bb;
}

__global__ void packK(const float* __restrict__ Wk, const float* __restrict__ bk,
                      bf16* __restrict__ Wc, float* __restrict__ b, int K) {
    int n = blockIdx.x, c = threadIdx.x;   // 256 rows: k
    Wc[(size_t)n * K + c] = __float2bfloat16(Wk[(size_t)c * 256 + n]);
    if (c == 0) b[n] = bk[n];
}

// ---------------- MFMA bf16 GEMM: out[M x ldo] = A[M x K] @ Wc^T + bias ----------------
// OUT8: write fp8-e4m3 bytes (for the k buffer) instead of bf16.
template<typename TA, bool OUT8>
__global__ void __launch_bounds__(256) gemm_mfma(
    const TA* __restrict__ A, int K,
    const bf16* __restrict__ Wc, const float* __restrict__ bias,
    int M, void* __restrict__ outp, int ldo)
{
    __shared__ short Al[64 * 40];
    __shared__ short Bl[64 * 40];
    int m0 = blockIdx.x * 64, n0 = blockIdx.y * 64;
    int tid = threadIdx.x;
    int w = tid >> 6, lane = tid & 63;
    int lr = tid >> 2, lc = (tid & 3) * 8;
    f32x4 acc[4] = {};

    for (int k0 = 0; k0 < K; k0 += 32) {
        __syncthreads();
        {
            int m = m0 + lr;
            uint4 val = make_uint4(0, 0, 0, 0);
            if (m < M) {
                if constexpr (sizeof(TA) == 4) {
                    const float4* ap = (const float4*)((const float*)A + (size_t)m * K + k0 + lc);
                    float4 f0 = ap[0], f1 = ap[1];
                    union { short s[8]; uint4 u; } t;
                    t.s[0] = f2s(f0.x); t.s[1] = f2s(f0.y); t.s[2] = f2s(f0.z); t.s[3] = f2s(f0.w);
                    t.s[4] = f2s(f1.x); t.s[5] = f2s(f1.y); t.s[6] = f2s(f1.z); t.s[7] = f2s(f1.w);
                    val = t.u;
                } else {
                    val = *(const uint4*)((const u16*)A + (size_t)m * K + k0 + lc);
                }
            }
            *(uint4*)&Al[lr * 40 + lc] = val;
        }
        *(uint4*)&Bl[lr * 40 + lc] = *(const uint4*)((const u16*)Wc + (size_t)(n0 + lr) * K + k0 + lc);
        __syncthreads();

        int am = lane & 15, aq = lane >> 4;
        bf16x8 af = *(const bf16x8*)&Al[(w * 16 + am) * 40 + aq * 8];
        #pragma unroll
        for (int t = 0; t < 4; t++) {
            bf16x8 bfr = *(const bf16x8*)&Bl[(t * 16 + am) * 40 + aq * 8];
            acc[t] = __builtin_amdgcn_mfma_f32_16x16x32_bf16(af, bfr, acc[t], 0, 0, 0);
        }
    }
    int cl = lane & 15, rq = lane >> 4;
    #pragma unroll
    for (int t = 0; t < 4; t++) {
        int c = n0 + t * 16 + cl;
        float bv = bias[c];
        #pragma unroll
        for (int r = 0; r < 4; r++) {
            int m = m0 + w * 16 + rq * 4 + r;
            if (m < M) {
                float v = acc[t][r] + bv;
                if constexpr (OUT8) {
                    int pk = __builtin_amdgcn_cvt_pk_fp8_f32(v, v, 0, false);
                    ((u8*)outp)[(size_t)m * ldo + c] = (u8)(pk & 0xFF);
                } else {
                    ((bf16*)outp)[(size_t)m * ldo + c] = __float2bfloat16(v);
                }
            }
        }
    }
}

// ---------------- fused edge-logit + node aggregation + epilogue ----------------
// One wave per node (4 nodes/block). Per edge: gather k8[src] (fp8), v[src] (bf16),
// eattr[eid]; logit = q.k + qwe.ea via 16-lane shfl reduce; alpha = exp(logit/8);
// accumulate alpha*v, alpha*ea, sum(alpha) in registers. No barriers anywhere.
__device__ __forceinline__ void edge_accum(
    int s, int eid,
    const u16* __restrict__ comb, const u8* __restrict__ k8, const float* __restrict__ eattr,
    int coff, int j16,
    float qf0, float qf1, float qf2, float qf3, float qwe_r,
    float& ss, float& av0, float& av1, float& av2, float& av3, float& ae)
{
    u32  kw = *(const u32*)(k8 + s * 256 + coff);
    uint2 vw = *(const uint2*)(comb + s * CW + 320 + coff);
    float ea = eattr[eid * 16 + j16];
    f32x2 k01 = __builtin_amdgcn_cvt_pk_f32_fp8(kw, false);
    f32x2 k23 = __builtin_amdgcn_cvt_pk_f32_fp8(kw, true);
    float part = qf0 * k01[0] + qf1 * k01[1] + qf2 * k23[0] + qf3 * k23[1] + qwe_r * ea;
    part += __shfl_xor(part, 1);
    part += __shfl_xor(part, 2);
    part += __shfl_xor(part, 4);
    part += __shfl_xor(part, 8);        // 16-lane (head-group) sum
    float alpha = __expf(part * 0.125f); // SCALE=1/8; max-subtraction cancels exactly
    ss += alpha;
    ae += alpha * ea;
    av0 += alpha * lo16f(vw.x); av1 += alpha * hi16f(vw.x);
    av2 += alpha * lo16f(vw.y); av3 += alpha * hi16f(vw.y);
}

__global__ void __launch_bounds__(256) node_fused(
    const int* __restrict__ rowptr, const int2* __restrict__ csr2,
    const float* __restrict__ eattr, const u16* __restrict__ comb,
    const u8* __restrict__ k8, const float* __restrict__ We,
    const float* __restrict__ lng, const float* __restrict__ lnb,
    bf16* __restrict__ outB, float* __restrict__ outF)
{
    int tid = threadIdx.x, w = tid >> 6, lane = tid & 63;
    int n = blockIdx.x * 4 + w;                  // 12500 * 4 == NNODES exactly
    int hg = lane >> 4, j16 = lane & 15, coff = 4 * lane;
    __shared__ float sAV[4][256];
    __shared__ float sAE[4][64];

    const u16* crow = comb + (size_t)n * CW;
    uint2 qv = *(const uint2*)(crow + coff);     // q channels coff..coff+3
    float qf0 = lo16f(qv.x), qf1 = hi16f(qv.x), qf2 = lo16f(qv.y), qf3 = hi16f(qv.y);
    float qwe_r = __uint_as_float((u32)crow[256 + lane] << 16);   // qwe[hg*16+j16] == [lane]

    int e0 = rowptr[n], e1 = rowptr[n + 1];
    float ss = 0.f, av0 = 0.f, av1 = 0.f, av2 = 0.f, av3 = 0.f, ae = 0.f;

    for (int base = e0; base < e1; base += 64) {
        int cnt = e1 - base; if (cnt > 64) cnt = 64;
        int2 meta = make_int2(0, 0);
        if (lane < cnt) meta = csr2[base + lane];
        int i = 0;
        for (; i + 3 < cnt; i += 4) {
            int s0 = __builtin_amdgcn_readlane(meta.x, i);
            int q0 = __builtin_amdgcn_readlane(meta.y, i);
            int s1 = __builtin_amdgcn_readlane(meta.x, i + 1);
            int q1 = __builtin_amdgcn_readlane(meta.y, i + 1);
            int s2 = __builtin_amdgcn_readlane(meta.x, i + 2);
            int q2 = __builtin_amdgcn_readlane(meta.y, i + 2);
            int s3 = __builtin_amdgcn_readlane(meta.x, i + 3);
            int q3 = __builtin_amdgcn_readlane(meta.y, i + 3);
            edge_accum(s0, q0, comb, k8, eattr, coff, j16, qf0, qf1, qf2, qf3, qwe_r, ss, av0, av1, av2, av3, ae);
            edge_accum(s1, q1, comb, k8, eattr, coff, j16, qf0, qf1, qf2, qf3, qwe_r, ss, av0, av1, av2, av3, ae);
            edge_accum(s2, q2, comb, k8, eattr, coff, j16, qf0, qf1, qf2, qf3, qwe_r, ss, av0, av1, av2, av3, ae);
            edge_accum(s3, q3, comb, k8, eattr, coff, j16, qf0, qf1, qf2, qf3, qwe_r, ss, av0, av1, av2, av3, ae);
        }
        for (; i < cnt; ++i) {
            int s0 = __builtin_amdgcn_readlane(meta.x, i);
            int q0 = __builtin_amdgcn_readlane(meta.y, i);
            edge_accum(s0, q0, comb, k8, eattr, coff, j16, qf0, qf1, qf2, qf3, qwe_r, ss, av0, av1, av2, av3, ae);
        }
    }

    // epilogue (all waves active; same-wave LDS transpose, no barrier)
    float inv = (ss > 0.f) ? 1.f / ss : 0.f;     // uniform within each 16-lane head group
    *(float4*)&sAV[w][coff] = make_float4(av0 * inv, av1 * inv, av2 * inv, av3 * inv);
    sAE[w][lane] = ae * inv;

    int d = lane;
    float val = 0.f;
    #pragma unroll
    for (int h = 0; h < 4; h++) {
        float xv = sAV[w][h * 64 + d];
        #pragma unroll
        for (int j = 0; j < 16; j++) xv += sAE[w][h * 16 + j] * We[j * HD + h * 64 + d];
        val += xv;
    }
    val = val * 0.25f + __uint_as_float((u32)crow[576 + d] << 16);   // head mean + skip

    float m = val;
    #pragma unroll
    for (int off = 1; off < 64; off <<= 1) m += __shfl_xor(m, off);
    m *= (1.f / 64.f);
    float diff = val - m;
    float vr = diff * diff;
    #pragma unroll
    for (int off = 1; off < 64; off <<= 1) vr += __shfl_xor(vr, off);
    vr *= (1.f / 64.f);
    float y = diff * rsqrtf(vr + 1e-5f) * lng[d] + lnb[d];
    float ge = 0.5f * y * (1.f + erff(y * 0.70710678118654752f));    // exact GELU
    if (outF) outF[(size_t)n * 64 + d] = ge;
    else      outB[(size_t)n * 64 + d] = __float2bfloat16(ge);
}

extern "C" void kernel_launch(void* const* d_in, const int* in_sizes, int n_in,
                              void* d_out, int out_size, void* d_ws, size_t ws_size,
                              hipStream_t stream)
{
    const float* x     = (const float*)d_in[0];
    const int*   eidx  = (const int*)d_in[1];
    const float* eattr = (const float*)d_in[2];
    struct P { const float *Wq,*bq,*Wk,*bk,*Wv,*bv,*We,*Ws,*bs; };
    P p[3];
    for (int l = 0; l < 3; l++) {
        int base = 3 + l * 9;
        p[l].Wq = (const float*)d_in[base + 0]; p[l].bq = (const float*)d_in[base + 1];
        p[l].Wk = (const float*)d_in[base + 2]; p[l].bk = (const float*)d_in[base + 3];
        p[l].Wv = (const float*)d_in[base + 4]; p[l].bv = (const float*)d_in[base + 5];
        p[l].We = (const float*)d_in[base + 6];
        p[l].Ws = (const float*)d_in[base + 7]; p[l].bs = (const float*)d_in[base + 8];
    }
    const float* lng = (const float*)d_in[30];
    const float* lnb = (const float*)d_in[31];

    // Workspace: ~91 MB
    char* ws = (char*)d_ws;
    size_t off = 0;
    auto alloc = [&](size_t bytes) { void* pp = ws + off; off += (bytes + 255) & ~(size_t)255; return pp; };
    int*   rowptr   = (int*)  alloc((NNODES + 1) * 4);
    int*   cursor   = (int*)  alloc(NNODES * 4);
    int*   deg      = (int*)  alloc(NNODES * 4);
    int*   blocksum = (int*)  alloc(256 * 4);
    int*   blockoff = (int*)  alloc(256 * 4);
    int2*  csr2     = (int2*) alloc((size_t)NEDGES * 8);        // 6.4 MB
    bf16*  hbuf     = (bf16*) alloc((size_t)NNODES * 64 * 2);   // 6.4 MB
    bf16*  comb     = (bf16*) alloc((size_t)NNODES * CW * 2);   // 64 MB: q|qwe|v|skip
    u8*    k8       = (u8*)   alloc((size_t)NNODES * 256);      // 12.8 MB fp8 k
    float* wqwe     = (float*)alloc((size_t)129 * 64 * 4);
    bf16*  Wc640    = (bf16*) alloc((size_t)640 * 128 * 2);
    bf16*  WcK      = (bf16*) alloc((size_t)256 * 128 * 2);
    float* b640     = (float*)alloc(640 * 4);
    float* bK       = (float*)alloc(256 * 4);
    (void)ws_size;

    const int* srcArr = eidx;           // edge_index[0]
    const int* dstArr = eidx + NEDGES;  // edge_index[1]

    // CSR build (multi-block scan)
    int NB = (NNODES + 255) / 256;
    (void)hipMemsetAsync(deg, 0, NNODES * 4, stream);
    hist_kernel<<<(NEDGES + 255) / 256, 256, 0, stream>>>(dstArr, deg, NEDGES);
    scanA<<<NB, 256, 0, stream>>>(deg, cursor, blocksum, NNODES);
    scanB<<<1, 256, 0, stream>>>(blocksum, blockoff, NB, rowptr, NNODES);
    scanC<<<NB, 256, 0, stream>>>(deg, cursor, blockoff, rowptr, cursor, NNODES);
    scatter_kernel<<<(NEDGES + 255) / 256, 256, 0, stream>>>(srcArr, dstArr, cursor, csr2, NEDGES);

    int gm = (NNODES + 63) / 64;
    int fins[3] = {128, 64, 64};

    const void* hin = x;
    for (int l = 0; l < 3; l++) {
        int FIN = fins[l];
        wqwe_kernel<<<FIN + 1, 64, 0, stream>>>(p[l].Wq, p[l].bq, p[l].We, wqwe, FIN);
        pack640<<<640, FIN, 0, stream>>>(p[l].Wq, p[l].bq, wqwe, p[l].Wv, p[l].bv,
                                         p[l].Ws, p[l].bs, Wc640, b640, FIN);
        packK<<<256, FIN, 0, stream>>>(p[l].Wk, p[l].bk, WcK, bK, FIN);
        // one GEMM for q|qwe|v|skip (bf16), one for k (fp8)
        if (l == 0) {
            gemm_mfma<float, false><<<dim3(gm, 10), 256, 0, stream>>>((const float*)hin, FIN, Wc640, b640, NNODES, comb, CW);
            gemm_mfma<float, true> <<<dim3(gm, 4),  256, 0, stream>>>((const float*)hin, FIN, WcK,   bK,   NNODES, k8, 256);
        } else {
            gemm_mfma<bf16, false><<<dim3(gm, 10), 256, 0, stream>>>((const bf16*)hin, FIN, Wc640, b640, NNODES, comb, CW);
            gemm_mfma<bf16, true> <<<dim3(gm, 4),  256, 0, stream>>>((const bf16*)hin, FIN, WcK,   bK,   NNODES, k8, 256);
        }
        // fused edge-logit + aggregation + LN + GELU
        node_fused<<<NNODES / 4, 256, 0, stream>>>(rowptr, csr2, eattr, (const u16*)comb, k8,
            p[l].We, lng, lnb, (l == 2) ? nullptr : hbuf, (l == 2) ? (float*)d_out : nullptr);
        hin = hbuf;
    }
}

// Round 2
// 688.533 us; speedup vs baseline: 1.4721x; 1.1041x over previous
//
#include <hip/hip_runtime.h>
#include <hip/hip_bf16.h>
#include <math.h>

#define NNODES 50000
#define NEDGES 800000
#define HD     256   // HEADS*DHEAD
#define CW     640   // comb width: q(256) | qwe(64) | v(256) | skip(64)
#define NTOT   896   // 640 bf16 rows + 256 fp8 (k) rows

typedef __hip_bfloat16 bf16;
typedef unsigned short u16;
typedef unsigned char  u8;
typedef unsigned int   u32;
typedef __attribute__((ext_vector_type(8))) short bf16x8;
typedef __attribute__((ext_vector_type(4))) float f32x4;
typedef __attribute__((ext_vector_type(2))) float f32x2;

__device__ __forceinline__ float lo16f(u32 u) { return __uint_as_float(u << 16); }
__device__ __forceinline__ float hi16f(u32 u) { return __uint_as_float(u & 0xFFFF0000u); }
__device__ __forceinline__ short f2s(float v) { __hip_bfloat16 h = __float2bfloat16(v); return *(short*)&h; }

// VALU cross-lane add within 16-lane groups: xor1,xor2 (quad_perm), xor4 (row_half_mirror), xor8 (row_mirror)
template<int CTRL>
__device__ __forceinline__ float dppadd(float x) {
    int t = __builtin_amdgcn_update_dpp(0, __float_as_int(x), CTRL, 0xF, 0xF, true);
    return x + __int_as_float(t);
}

// ---------------- CSR build ----------------
__global__ void hist_kernel(const int* __restrict__ dst, int* __restrict__ deg, int E) {
    int e = blockIdx.x * 256 + threadIdx.x;
    if (e < E) atomicAdd(&deg[dst[e]], 1);
}

__global__ void scanA(const int* __restrict__ deg, int* __restrict__ locincl,
                      int* __restrict__ blocksum, int n) {
    int tid = threadIdx.x;
    int i = blockIdx.x * 256 + tid;
    int v = (i < n) ? deg[i] : 0;
    int lane = tid & 63, w = tid >> 6;
    int s = v;
    #pragma unroll
    for (int off = 1; off < 64; off <<= 1) {
        int t = __shfl_up(s, off);
        if (lane >= off) s += t;
    }
    __shared__ int wsum[4];
    if (lane == 63) wsum[w] = s;
    __syncthreads();
    for (int ww = 0; ww < w; ww++) s += wsum[ww];
    if (i < n) locincl[i] = s;
    if (tid == 255) blocksum[blockIdx.x] = s;
}

__global__ void scanB(const int* __restrict__ blocksum, int* __restrict__ blockoff,
                      int nb, int* __restrict__ rowptr, int n) {
    int tid = threadIdx.x;
    int v = (tid < nb) ? blocksum[tid] : 0;
    int lane = tid & 63, w = tid >> 6;
    int s = v;
    #pragma unroll
    for (int off = 1; off < 64; off <<= 1) {
        int t = __shfl_up(s, off);
        if (lane >= off) s += t;
    }
    __shared__ int wsum[4];
    if (lane == 63) wsum[w] = s;
    __syncthreads();
    for (int ww = 0; ww < w; ww++) s += wsum[ww];
    if (tid < nb) blockoff[tid] = s - v;
    if (tid == 255) rowptr[n] = s;
}

__global__ void scanC(const int* __restrict__ deg, const int* __restrict__ locincl,
                      const int* __restrict__ blockoff,
                      int* __restrict__ rowptr, int* __restrict__ cursor, int n) {
    int i = blockIdx.x * 256 + threadIdx.x;
    if (i < n) {
        int ex = locincl[i] - deg[i] + blockoff[blockIdx.x];
        rowptr[i] = ex;
        cursor[i] = ex;
    }
}

__global__ void scatter_kernel(const int* __restrict__ src, const int* __restrict__ dst,
                               int* __restrict__ cursor, int2* __restrict__ csr2, int E) {
    int e = blockIdx.x * 256 + threadIdx.x;
    if (e < E) {
        int d = dst[e];
        int p = atomicAdd(&cursor[d], 1);
        csr2[p] = make_int2(src[e], e);
    }
}

// ---- one pack kernel: 896 rows n-major bf16 [NTOT][K] + fp32 bias ----
// rows: q(0..255) | qwe(256..319, computed inline) | v(320..575) | skip(576..639) | k(640..895)
__global__ void pack_all(const float* __restrict__ Wq, const float* __restrict__ bq,
                         const float* __restrict__ Wk, const float* __restrict__ bk,
                         const float* __restrict__ Wv, const float* __restrict__ bv,
                         const float* __restrict__ We,
                         const float* __restrict__ Ws, const float* __restrict__ bs,
                         bf16* __restrict__ Wc, float* __restrict__ b, int K) {
    int n = blockIdx.x, c = threadIdx.x;
    float v, bb;
    if (n < 256)      { v = Wq[(size_t)c * 256 + n];         bb = bq[n]; }
    else if (n < 320) {
        int t = n - 256, h = t >> 4, j = t & 15;
        float s = 0.f, sb = 0.f;
        #pragma unroll 8
        for (int d = 0; d < 64; d++) {
            float wv = We[j * HD + h * 64 + d];
            s += Wq[(size_t)c * 256 + h * 64 + d] * wv;
            sb += bq[h * 64 + d] * wv;
        }
        v = s; bb = sb;
    }
    else if (n < 576) { v = Wv[(size_t)c * 256 + (n - 320)]; bb = bv[n - 320]; }
    else if (n < 640) { v = Ws[(size_t)c * 64  + (n - 576)]; bb = bs[n - 576]; }
    else              { v = Wk[(size_t)c * 256 + (n - 640)]; bb = bk[n - 640]; }
    Wc[(size_t)n * K + c] = __float2bfloat16(v);
    if (c == 0) b[n] = bb;
}

// ---------------- fused MFMA GEMM: comb[M x 640] (bf16) + k8[M x 256] (fp8) ----------------
// A-fragments live in registers for the whole block; B chunks staged in XOR-swizzled LDS.
// mfma(bfr, af): output reg-index walks N -> 4 consecutive channels per lane -> packed stores.
template<typename TA, int K>
__global__ void __launch_bounds__(256) gemm_fused(
    const TA* __restrict__ A, const bf16* __restrict__ Wc, const float* __restrict__ bias,
    bf16* __restrict__ comb, u8* __restrict__ k8)
{
    constexpr int KS  = K / 32;   // MFMA k-steps
    constexpr int CPR = K / 8;    // 16B granules per B row
    __shared__ short Bl[64 * K];
    int tid = threadIdx.x, w = tid >> 6, lane = tid & 63;
    int cl = lane & 15, aq = lane >> 4;
    int m = blockIdx.x * 64 + w * 16 + cl;
    int rowc = (m < NNODES) ? m : (NNODES - 1);

    bf16x8 af[KS];
    if constexpr (sizeof(TA) == 4) {
        const float* ar = (const float*)A + (size_t)rowc * K;
        #pragma unroll
        for (int ks = 0; ks < KS; ks++) {
            const float4* ap = (const float4*)(ar + ks * 32 + aq * 8);
            float4 f0 = ap[0], f1 = ap[1];
            union { short s[8]; bf16x8 v; } t;
            t.s[0] = f2s(f0.x); t.s[1] = f2s(f0.y); t.s[2] = f2s(f0.z); t.s[3] = f2s(f0.w);
            t.s[4] = f2s(f1.x); t.s[5] = f2s(f1.y); t.s[6] = f2s(f1.z); t.s[7] = f2s(f1.w);
            af[ks] = t.v;
        }
    } else {
        const u16* ar = (const u16*)A + (size_t)rowc * K;
        #pragma unroll
        for (int ks = 0; ks < KS; ks++) af[ks] = *(const bf16x8*)(ar + ks * 32 + aq * 8);
    }

    for (int chunk = 0; chunk < 14; chunk++) {
        int n0 = chunk * 64;
        __syncthreads();
        #pragma unroll
        for (int p = 0; p < CPR / 4; p++) {
            int slot = tid + p * 256;
            int row = slot / CPR, j = slot % CPR;
            *(uint4*)&Bl[row * K + ((j ^ (row & 7)) << 3)] =
                *(const uint4*)((const u16*)Wc + (size_t)(n0 + row) * K + (j << 3));
        }
        __syncthreads();

        f32x4 acc[4] = {};
        #pragma unroll
        for (int t = 0; t < 4; t++) {
            #pragma unroll
            for (int ks = 0; ks < KS; ks++) {
                int g = ((ks * 4 + aq) ^ (cl & 7)) << 3;
                bf16x8 bfr = *(const bf16x8*)&Bl[(t * 16 + cl) * K + g];
                acc[t] = __builtin_amdgcn_mfma_f32_16x16x32_bf16(bfr, af[ks], acc[t], 0, 0, 0);
            }
        }

        if (m < NNODES) {
            #pragma unroll
            for (int t = 0; t < 4; t++) {
                float4 bv = *(const float4*)&bias[n0 + t * 16 + aq * 4];
                float v0 = acc[t][0] + bv.x, v1 = acc[t][1] + bv.y;
                float v2 = acc[t][2] + bv.z, v3 = acc[t][3] + bv.w;
                if (chunk < 10) {
                    u32 lo = (u32)(u16)f2s(v0) | ((u32)(u16)f2s(v1) << 16);
                    u32 hi = (u32)(u16)f2s(v2) | ((u32)(u16)f2s(v3) << 16);
                    *(uint2*)((u16*)comb + (size_t)m * CW + n0 + t * 16 + aq * 4) = make_uint2(lo, hi);
                } else {
                    u32 pk = __builtin_amdgcn_cvt_pk_fp8_f32(v0, v1, 0, false);
                    pk = __builtin_amdgcn_cvt_pk_fp8_f32(v2, v3, pk, true);
                    *(u32*)(k8 + (size_t)m * 256 + (n0 - 640) + t * 16 + aq * 4) = pk;
                }
            }
        }
    }
}

// ---------------- fused edge-logit + node aggregation + epilogue ----------------
__device__ __forceinline__ void edge_accum(
    u32 s, u32 eid,
    const char* __restrict__ comb_b, const char* __restrict__ k8_b, const char* __restrict__ eattr_b,
    u32 koff, u32 voff, u32 eoff,
    float qf0, float qf1, float qf2, float qf3, float qwe_r,
    float& ss, float& av0, float& av1, float& av2, float& av3, float& ae)
{
    u32   kw = *(const u32*)  (k8_b   + ((s << 8) + koff));
    uint2 vw = *(const uint2*)(comb_b + (s * 1280u + voff));
    float ea = *(const float*)(eattr_b + ((eid << 6) + eoff));
    f32x2 k01 = __builtin_amdgcn_cvt_pk_f32_fp8(kw, false);
    f32x2 k23 = __builtin_amdgcn_cvt_pk_f32_fp8(kw, true);
    float part = qf0 * k01[0] + qf1 * k01[1] + qf2 * k23[0] + qf3 * k23[1] + qwe_r * ea;
    part = dppadd<0xB1>(part);    // quad_perm [1,0,3,2]  == xor 1
    part = dppadd<0x4E>(part);    // quad_perm [2,3,0,1]  == xor 2
    part = dppadd<0x141>(part);   // row_half_mirror      == xor 4 (post-quad-reduce)
    part = dppadd<0x140>(part);   // row_mirror           == xor 8 (post-half-reduce)
    float alpha = __expf(part * 0.125f);   // SCALE=1/8; max-subtraction cancels exactly
    ss += alpha;
    ae += alpha * ea;
    av0 += alpha * lo16f(vw.x); av1 += alpha * hi16f(vw.x);
    av2 += alpha * lo16f(vw.y); av3 += alpha * hi16f(vw.y);
}

__global__ void __launch_bounds__(256) node_fused(
    const int* __restrict__ rowptr, const int2* __restrict__ csr2,
    const float* __restrict__ eattr, const u16* __restrict__ comb,
    const u8* __restrict__ k8, const float* __restrict__ We,
    const float* __restrict__ lng, const float* __restrict__ lnb,
    bf16* __restrict__ outB, float* __restrict__ outF)
{
    int tid = threadIdx.x, w = tid >> 6, lane = tid & 63;
    int n = blockIdx.x * 4 + w;                  // 12500 * 4 == NNODES exactly
    int hg = lane >> 4, j16 = lane & 15, coff = 4 * lane;
    __shared__ float sAV[4][256];
    __shared__ float sAE[4][64];

    const u16* crow = comb + (size_t)n * CW;
    uint2 qv = *(const uint2*)(crow + coff);     // q channels coff..coff+3
    float qf0 = lo16f(qv.x), qf1 = hi16f(qv.x), qf2 = lo16f(qv.y), qf3 = hi16f(qv.y);
    float qwe_r = __uint_as_float((u32)crow[256 + lane] << 16);   // qwe[hg*16+j16] == [lane]

    const char* comb_b  = (const char*)comb;
    const char* k8_b    = (const char*)k8;
    const char* eattr_b = (const char*)eattr;
    u32 koff = (u32)coff;                 // fp8 bytes
    u32 voff = 640u + ((u32)coff << 1);   // v starts at channel 320 -> byte 640
    u32 eoff = (u32)j16 << 2;

    int e0 = rowptr[n], e1 = rowptr[n + 1];
    float ss = 0.f, av0 = 0.f, av1 = 0.f, av2 = 0.f, av3 = 0.f, ae = 0.f;

    for (int base = e0; base < e1; base += 64) {
        int cnt = e1 - base; if (cnt > 64) cnt = 64;
        int2 meta = make_int2(0, 0);
        if (lane < cnt) meta = csr2[base + lane];
        int i = 0;
        for (; i + 3 < cnt; i += 4) {
            u32 s0 = __builtin_amdgcn_readlane(meta.x, i);
            u32 q0 = __builtin_amdgcn_readlane(meta.y, i);
            u32 s1 = __builtin_amdgcn_readlane(meta.x, i + 1);
            u32 q1 = __builtin_amdgcn_readlane(meta.y, i + 1);
            u32 s2 = __builtin_amdgcn_readlane(meta.x, i + 2);
            u32 q2 = __builtin_amdgcn_readlane(meta.y, i + 2);
            u32 s3 = __builtin_amdgcn_readlane(meta.x, i + 3);
            u32 q3 = __builtin_amdgcn_readlane(meta.y, i + 3);
            edge_accum(s0, q0, comb_b, k8_b, eattr_b, koff, voff, eoff, qf0, qf1, qf2, qf3, qwe_r, ss, av0, av1, av2, av3, ae);
            edge_accum(s1, q1, comb_b, k8_b, eattr_b, koff, voff, eoff, qf0, qf1, qf2, qf3, qwe_r, ss, av0, av1, av2, av3, ae);
            edge_accum(s2, q2, comb_b, k8_b, eattr_b, koff, voff, eoff, qf0, qf1, qf2, qf3, qwe_r, ss, av0, av1, av2, av3, ae);
            edge_accum(s3, q3, comb_b, k8_b, eattr_b, koff, voff, eoff, qf0, qf1, qf2, qf3, qwe_r, ss, av0, av1, av2, av3, ae);
        }
        for (; i < cnt; ++i) {
            u32 s0 = __builtin_amdgcn_readlane(meta.x, i);
            u32 q0 = __builtin_amdgcn_readlane(meta.y, i);
            edge_accum(s0, q0, comb_b, k8_b, eattr_b, koff, voff, eoff, qf0, qf1, qf2, qf3, qwe_r, ss, av0, av1, av2, av3, ae);
        }
    }

    // epilogue (all waves active; same-wave LDS transpose, no barrier)
    float inv = (ss > 0.f) ? 1.f / ss : 0.f;     // uniform within each 16-lane head group
    *(float4*)&sAV[w][coff] = make_float4(av0 * inv, av1 * inv, av2 * inv, av3 * inv);
    sAE[w][lane] = ae * inv;

    int d = lane;
    float val = 0.f;
    #pragma unroll
    for (int h = 0; h < 4; h++) {
        float xv = sAV[w][h * 64 + d];
        #pragma unroll
        for (int j = 0; j < 16; j++) xv += sAE[w][h * 16 + j] * We[j * HD + h * 64 + d];
        val += xv;
    }
    val = val * 0.25f + __uint_as_float((u32)crow[576 + d] << 16);   // head mean + skip

    float m = val;
    #pragma unroll
    for (int off = 1; off < 64; off <<= 1) m += __shfl_xor(m, off);
    m *= (1.f / 64.f);
    float diff = val - m;
    float vr = diff * diff;
    #pragma unroll
    for (int off = 1; off < 64; off <<= 1) vr += __shfl_xor(vr, off);
    vr *= (1.f / 64.f);
    float y = diff * rsqrtf(vr + 1e-5f) * lng[d] + lnb[d];
    float ge = 0.5f * y * (1.f + erff(y * 0.70710678118654752f));    // exact GELU
    if (outF) outF[(size_t)n * 64 + d] = ge;
    else      outB[(size_t)n * 64 + d] = __float2bfloat16(ge);
}

extern "C" void kernel_launch(void* const* d_in, const int* in_sizes, int n_in,
                              void* d_out, int out_size, void* d_ws, size_t ws_size,
                              hipStream_t stream)
{
    const float* x     = (const float*)d_in[0];
    const int*   eidx  = (const int*)d_in[1];
    const float* eattr = (const float*)d_in[2];
    struct P { const float *Wq,*bq,*Wk,*bk,*Wv,*bv,*We,*Ws,*bs; };
    P p[3];
    for (int l = 0; l < 3; l++) {
        int base = 3 + l * 9;
        p[l].Wq = (const float*)d_in[base + 0]; p[l].bq = (const float*)d_in[base + 1];
        p[l].Wk = (const float*)d_in[base + 2]; p[l].bk = (const float*)d_in[base + 3];
        p[l].Wv = (const float*)d_in[base + 4]; p[l].bv = (const float*)d_in[base + 5];
        p[l].We = (const float*)d_in[base + 6];
        p[l].Ws = (const float*)d_in[base + 7]; p[l].bs = (const float*)d_in[base + 8];
    }
    const float* lng = (const float*)d_in[30];
    const float* lnb = (const float*)d_in[31];

    // Workspace: ~90 MB
    char* ws = (char*)d_ws;
    size_t off = 0;
    auto alloc = [&](size_t bytes) { void* pp = ws + off; off += (bytes + 255) & ~(size_t)255; return pp; };
    int*   rowptr   = (int*)  alloc((NNODES + 1) * 4);
    int*   cursor   = (int*)  alloc(NNODES * 4);
    int*   deg      = (int*)  alloc(NNODES * 4);
    int*   blocksum = (int*)  alloc(256 * 4);
    int*   blockoff = (int*)  alloc(256 * 4);
    int2*  csr2     = (int2*) alloc((size_t)NEDGES * 8);        // 6.4 MB
    bf16*  hbuf     = (bf16*) alloc((size_t)NNODES * 64 * 2);   // 6.4 MB
    bf16*  comb     = (bf16*) alloc((size_t)NNODES * CW * 2);   // 64 MB: q|qwe|v|skip
    u8*    k8       = (u8*)   alloc((size_t)NNODES * 256);      // 12.8 MB fp8 k
    bf16*  Wc       = (bf16*) alloc((size_t)NTOT * 128 * 2);    // 229 KB
    float* b896     = (float*)alloc(NTOT * 4);
    (void)ws_size;

    const int* srcArr = eidx;           // edge_index[0]
    const int* dstArr = eidx + NEDGES;  // edge_index[1]

    // CSR build (multi-block scan)
    int NB = (NNODES + 255) / 256;
    (void)hipMemsetAsync(deg, 0, NNODES * 4, stream);
    hist_kernel<<<(NEDGES + 255) / 256, 256, 0, stream>>>(dstArr, deg, NEDGES);
    scanA<<<NB, 256, 0, stream>>>(deg, cursor, blocksum, NNODES);
    scanB<<<1, 256, 0, stream>>>(blocksum, blockoff, NB, rowptr, NNODES);
    scanC<<<NB, 256, 0, stream>>>(deg, cursor, blockoff, rowptr, cursor, NNODES);
    scatter_kernel<<<(NEDGES + 255) / 256, 256, 0, stream>>>(srcArr, dstArr, cursor, csr2, NEDGES);

    int gm = (NNODES + 63) / 64;   // 782
    int fins[3] = {128, 64, 64};

    const void* hin = x;
    for (int l = 0; l < 3; l++) {
        int FIN = fins[l];
        pack_all<<<NTOT, FIN, 0, stream>>>(p[l].Wq, p[l].bq, p[l].Wk, p[l].bk,
                                           p[l].Wv, p[l].bv, p[l].We, p[l].Ws, p[l].bs,
                                           Wc, b896, FIN);
        if (l == 0) gemm_fused<float, 128><<<gm, 256, 0, stream>>>((const float*)hin, Wc, b896, comb, k8);
        else        gemm_fused<bf16,  64><<<gm, 256, 0, stream>>>((const bf16*)hin,  Wc, b896, comb, k8);
        node_fused<<<NNODES / 4, 256, 0, stream>>>(rowptr, csr2, eattr, (const u16*)comb, k8,
            p[l].We, lng, lnb, (l == 2) ? nullptr : hbuf, (l == 2) ? (float*)d_out : nullptr);
        hin = hbuf;
    }
}